// Round 5
// baseline (5526.597 us; speedup 1.0000x reference)
//
#include <hip/hip_runtime.h>

#define Tn 512
#define Bn 64
#define Nn 1024
#define Hn 512

typedef __attribute__((ext_vector_type(8))) short short8;
typedef __attribute__((ext_vector_type(4))) float f32x4;

__device__ __forceinline__ unsigned short f2bf_hi(float x) {
  unsigned u = __builtin_bit_cast(unsigned, x);
  unsigned r = u + 0x7FFFu + ((u >> 16) & 1u);  // RNE
  return (unsigned short)(r >> 16);
}
__device__ __forceinline__ float bf2f(unsigned short b) {
  unsigned u = ((unsigned)b) << 16;
  return __builtin_bit_cast(float, u);
}

// ---------------------------------------------------------------------------
// k0: SP[b][j] = sum_i s[b][i] * W1[j][i]  + b1[j]    (first half of W1 rows)
// ---------------------------------------------------------------------------
__global__ __launch_bounds__(256) void k0_sproj(const float* __restrict__ s,
    const float* __restrict__ W1, const float* __restrict__ b1,
    float* __restrict__ SP) {
  const int b = blockIdx.x;
  const int tid = threadIdx.x;
  __shared__ float sl[Nn];
  for (int i = tid; i < Nn; i += 256) sl[i] = s[(size_t)b * Nn + i];
  __syncthreads();
#pragma unroll
  for (int qq = 0; qq < 4; ++qq) {
    const int j = qq * 256 + tid;
    const float* w = W1 + (size_t)j * (2 * Nn);
    float acc = 0.f;
    for (int i = 0; i < Nn; i += 4) {
      const float4 wv = *(const float4*)(w + i);
      acc += sl[i] * wv.x + sl[i + 1] * wv.y + sl[i + 2] * wv.z + sl[i + 3] * wv.w;
    }
    SP[(size_t)b * Nn + j] = acc + b1[j];
  }
}

// ---------------------------------------------------------------------------
// k1_mfma: XW[m][j] = sum_k X[m][k]*Wcat[j][k] + bias[j]  (UNCHANGED from R4)
// ---------------------------------------------------------------------------
#define LDA 40
__global__ __launch_bounds__(256) void k1_mfma(const float* __restrict__ X,
    const float* __restrict__ Wf, const float* __restrict__ Wb,
    const float* __restrict__ bif, const float* __restrict__ bib,
    float* __restrict__ XW) {
  __shared__ __align__(16) unsigned short Ahi[128 * LDA];
  __shared__ __align__(16) unsigned short Alo[128 * LDA];
  __shared__ __align__(16) unsigned short Bhi[128 * LDA];
  __shared__ __align__(16) unsigned short Blo[128 * LDA];
  const int tid = threadIdx.x;
  const int n0 = blockIdx.x * 128;
  const int m0 = blockIdx.y * 128;
  const int lane = tid & 63;
  const int w = tid >> 6;
  const int mw = (w >> 1) * 64, nw = (w & 1) * 64;
  const int l15 = lane & 15, l4 = lane >> 4;

  const float* bsrc;
  const float* bias_base;
  if (n0 < 512) { bsrc = Wf + (size_t)n0 * Nn; bias_base = bif + n0; }
  else          { bsrc = Wb + (size_t)(n0 - 512) * Nn; bias_base = bib + (n0 - 512); }

  const int srow = tid >> 1, scol = (tid & 1) * 16;
  const float* ag = X + (size_t)(m0 + srow) * Nn + scol;
  const float* bg = bsrc + (size_t)srow * Nn + scol;

  f32x4 acc[4][4];
#pragma unroll
  for (int i = 0; i < 4; ++i)
#pragma unroll
    for (int j = 0; j < 4; ++j) acc[i][j] = (f32x4){0.f, 0.f, 0.f, 0.f};

  for (int kt = 0; kt < 32; ++kt) {
    const int k0 = kt * 32;
    float4 av[4], bv[4];
#pragma unroll
    for (int c = 0; c < 4; ++c) {
      av[c] = *(const float4*)(ag + k0 + c * 4);
      bv[c] = *(const float4*)(bg + k0 + c * 4);
    }
    __syncthreads();
#pragma unroll
    for (int c = 0; c < 4; ++c) {
      const float a4[4] = {av[c].x, av[c].y, av[c].z, av[c].w};
      const float b4[4] = {bv[c].x, bv[c].y, bv[c].z, bv[c].w};
      ushort4 ah, al, bh, bl;
      unsigned short* ahp = (unsigned short*)&ah;
      unsigned short* alp = (unsigned short*)&al;
      unsigned short* bhp = (unsigned short*)&bh;
      unsigned short* blp = (unsigned short*)&bl;
#pragma unroll
      for (int e = 0; e < 4; ++e) {
        const unsigned short h = f2bf_hi(a4[e]);
        ahp[e] = h; alp[e] = f2bf_hi(a4[e] - bf2f(h));
        const unsigned short g = f2bf_hi(b4[e]);
        bhp[e] = g; blp[e] = f2bf_hi(b4[e] - bf2f(g));
      }
      const int off = srow * LDA + scol + c * 4;
      *(ushort4*)&Ahi[off] = ah; *(ushort4*)&Alo[off] = al;
      *(ushort4*)&Bhi[off] = bh; *(ushort4*)&Blo[off] = bl;
    }
    __syncthreads();
    short8 afh[4], afl[4];
#pragma unroll
    for (int mi = 0; mi < 4; ++mi) {
      const int off = (mw + mi * 16 + l15) * LDA + l4 * 8;
      afh[mi] = *(const short8*)&Ahi[off];
      afl[mi] = *(const short8*)&Alo[off];
    }
#pragma unroll
    for (int ni = 0; ni < 4; ++ni) {
      const int off = (nw + ni * 16 + l15) * LDA + l4 * 8;
      const short8 bfh = *(const short8*)&Bhi[off];
      const short8 bfl = *(const short8*)&Blo[off];
#pragma unroll
      for (int mi = 0; mi < 4; ++mi) {
        acc[mi][ni] = __builtin_amdgcn_mfma_f32_16x16x32_bf16(afh[mi], bfh, acc[mi][ni], 0, 0, 0);
        acc[mi][ni] = __builtin_amdgcn_mfma_f32_16x16x32_bf16(afh[mi], bfl, acc[mi][ni], 0, 0, 0);
        acc[mi][ni] = __builtin_amdgcn_mfma_f32_16x16x32_bf16(afl[mi], bfh, acc[mi][ni], 0, 0, 0);
      }
    }
  }
#pragma unroll
  for (int ni = 0; ni < 4; ++ni) {
    const int col = n0 + nw + ni * 16 + l15;
    const float bias = bias_base[nw + ni * 16 + l15];
#pragma unroll
    for (int mi = 0; mi < 4; ++mi) {
      const int row = m0 + mw + mi * 16 + l4 * 4;
#pragma unroll
      for (int reg = 0; reg < 4; ++reg)
        XW[(size_t)(row + reg) * Nn + col] = acc[mi][ni][reg] + bias;
    }
  }
}

// ---------------------------------------------------------------------------
// k2_scan_mfma: bidirectional RNN scan, 64 WGs = 2 dir x 32 rgroups(16 rows).
//   Whh slice held in VGPRs as bf16 hi/lo B-frags for ALL 512 steps (constant).
//   h stored as bf16 hi/lo pairs == MFMA A-frag format; consumer loads frags
//   directly from LLC via relaxed-agent atomics (no fence, no LDS staging).
//   Per wave per step: 64 8B A-loads + 48 MFMA (3-split, 3 acc chains).
// ---------------------------------------------------------------------------
#define K2W 32
__global__ __launch_bounds__(256, 1) void k2_scan_mfma(
    const float* __restrict__ XW,
    const float* __restrict__ Whh_f, const float* __restrict__ Whh_b,
    const float* __restrict__ bhh_f, const float* __restrict__ bhh_b,
    unsigned short* __restrict__ Hhi, unsigned short* __restrict__ Hlo,
    int* __restrict__ FL) {
  const int wg = blockIdx.x;
  const int dir = wg >> 5;
  const int rg = wg & 31;          // rows [rg*16, rg*16+16)
  const int tid = threadIdx.x;
  const int lane = tid & 63;
  const int wv = tid >> 6;         // wave id -> batch tile
  const int l15 = lane & 15, l4 = lane >> 4;
  const int mbase = wv * 16;
  const float* Whh = dir ? Whh_b : Whh_f;
  const float* bhh = dir ? bhh_b : bhh_f;

  // --- load Whh B-frags into VGPRs (once) ---
  short8 Bh[16], Bl[16];
  {
    const float* wr = Whh + (size_t)(rg * 16 + l15) * Hn;
#pragma unroll
    for (int kt = 0; kt < 16; ++kt) {
      const float4 w0 = *(const float4*)(wr + kt * 32 + l4 * 8);
      const float4 w1 = *(const float4*)(wr + kt * 32 + l4 * 8 + 4);
      const float wf[8] = {w0.x, w0.y, w0.z, w0.w, w1.x, w1.y, w1.z, w1.w};
      union { unsigned short u[8]; short8 v; } hh, ll;
#pragma unroll
      for (int e = 0; e < 8; ++e) {
        const unsigned short h = f2bf_hi(wf[e]);
        hh.u[e] = h; ll.u[e] = f2bf_hi(wf[e] - bf2f(h));
      }
      Bh[kt] = hh.v; Bl[kt] = ll.v;
    }
  }
  const float bhh_c = bhh[rg * 16 + l15];
  const int colg = dir * 512 + rg * 16 + l15;  // global feature col (C layout)

  for (int t = 0; t < Tn; ++t) {
    const int trow = dir ? (Tn - 1 - t) : t;
    // XW prefetch (independent of h[t-1]; overlaps the poll)
    float xwv[4];
#pragma unroll
    for (int reg = 0; reg < 4; ++reg)
      xwv[reg] = XW[((size_t)trow * Bn + mbase + l4 * 4 + reg) * Nn + colg];

    f32x4 a0 = {0.f, 0.f, 0.f, 0.f}, a1 = a0, a2 = a0;
    if (t > 0) {
      {  // per-wave poll of all 32 producer flags (coalesced, relaxed)
        int* fp = FL + (size_t)(((dir << 9) | (t - 1))) * K2W;
        while (true) {
          const int v = __hip_atomic_load(fp + (lane & 31), __ATOMIC_RELAXED,
                                          __HIP_MEMORY_SCOPE_AGENT);
          if (__all(v != 0)) break;
          __builtin_amdgcn_s_sleep(1);
        }
      }
      asm volatile("" ::: "memory");  // compiler fence: no load hoisting above poll
      const int hprow = dir ? (Tn - t) : (t - 1);
      // A-frag base: row = batch (mbase+l15), cols = dir*512 + kt*32 + l4*8
      const unsigned long long* hh = (const unsigned long long*)(
          Hhi + ((size_t)hprow * Bn + mbase + l15) * Nn + dir * 512);
      const unsigned long long* hl = (const unsigned long long*)(
          Hlo + ((size_t)hprow * Bn + mbase + l15) * Nn + dir * 512);
      short8 ah[16], al[16];
#pragma unroll
      for (int kt = 0; kt < 16; ++kt) {
        const int o = kt * 8 + l4 * 2;  // in 8B units
        union { unsigned long long u[2]; short8 v; } A, L;
        A.u[0] = __hip_atomic_load(hh + o, __ATOMIC_RELAXED, __HIP_MEMORY_SCOPE_AGENT);
        A.u[1] = __hip_atomic_load(hh + o + 1, __ATOMIC_RELAXED, __HIP_MEMORY_SCOPE_AGENT);
        L.u[0] = __hip_atomic_load(hl + o, __ATOMIC_RELAXED, __HIP_MEMORY_SCOPE_AGENT);
        L.u[1] = __hip_atomic_load(hl + o + 1, __ATOMIC_RELAXED, __HIP_MEMORY_SCOPE_AGENT);
        ah[kt] = A.v; al[kt] = L.v;
      }
#pragma unroll
      for (int kt = 0; kt < 16; ++kt) {
        a0 = __builtin_amdgcn_mfma_f32_16x16x32_bf16(ah[kt], Bh[kt], a0, 0, 0, 0);
        a1 = __builtin_amdgcn_mfma_f32_16x16x32_bf16(ah[kt], Bl[kt], a1, 0, 0, 0);
        a2 = __builtin_amdgcn_mfma_f32_16x16x32_bf16(al[kt], Bh[kt], a2, 0, 0, 0);
      }
    }
    // epilogue: C layout col=lane&15(row r), row=(lane>>4)*4+reg(batch)
#pragma unroll
    for (int reg = 0; reg < 4; ++reg) {
      const float pre = a0[reg] + a1[reg] + a2[reg] + xwv[reg] + bhh_c;
      const float h = tanhf(pre);
      const unsigned short hi = f2bf_hi(h);
      const unsigned short lo = f2bf_hi(h - bf2f(hi));
      const size_t addr = ((size_t)trow * Bn + mbase + l4 * 4 + reg) * Nn + colg;
      __hip_atomic_store(Hhi + addr, hi, __ATOMIC_RELAXED, __HIP_MEMORY_SCOPE_AGENT);
      __hip_atomic_store(Hlo + addr, lo, __ATOMIC_RELAXED, __HIP_MEMORY_SCOPE_AGENT);
    }
    asm volatile("s_waitcnt vmcnt(0)" ::: "memory");
    __syncthreads();
    if (tid == 0)
      __hip_atomic_store(FL + (size_t)(((dir << 9) | t)) * K2W + rg, 1,
                         __ATOMIC_RELAXED, __HIP_MEMORY_SCOPE_AGENT);
  }
}

// ---------------------------------------------------------------------------
// k3_mfma: EP[m] += sum_j W2[j]*tanh(sum_k H[m][k]*W1[j][N+k] + SP[b][j])
//   A-side now sourced directly from Hhi/Hlo (already bf16 hi/lo -- no cvt).
// ---------------------------------------------------------------------------
__global__ __launch_bounds__(256) void k3_mfma(
    const unsigned short* __restrict__ Hhi, const unsigned short* __restrict__ Hlo,
    const float* __restrict__ W1, const float* __restrict__ SP,
    const float* __restrict__ W2, float* __restrict__ EP) {
  __shared__ __align__(16) unsigned short Ahi[128 * LDA];
  __shared__ __align__(16) unsigned short Alo[128 * LDA];
  __shared__ __align__(16) unsigned short Bhi[128 * LDA];
  __shared__ __align__(16) unsigned short Blo[128 * LDA];
  __shared__ __align__(16) float SPs[64 * 128];
  const int tid = threadIdx.x;
  const int n0 = blockIdx.x * 128;
  const int m0 = blockIdx.y * 128;
  const int lane = tid & 63;
  const int w = tid >> 6;
  const int mw = (w >> 1) * 64, nw = (w & 1) * 64;
  const int l15 = lane & 15, l4 = lane >> 4;

  {
    const int r64 = tid >> 2, c0 = (tid & 3) * 32;
    const float* sps = SP + (size_t)r64 * Nn + n0 + c0;
    float* spd = &SPs[r64 * 128 + c0];
#pragma unroll
    for (int c = 0; c < 8; ++c) *(float4*)(spd + c * 4) = *(const float4*)(sps + c * 4);
  }

  const int srow = tid >> 1, scol = (tid & 1) * 16;
  const unsigned short* aghi = Hhi + (size_t)(m0 + srow) * Nn + scol;
  const unsigned short* aglo = Hlo + (size_t)(m0 + srow) * Nn + scol;
  const float* bg = W1 + (size_t)(n0 + srow) * (2 * Nn) + Nn + scol;

  f32x4 acc[4][4];
#pragma unroll
  for (int i = 0; i < 4; ++i)
#pragma unroll
    for (int j = 0; j < 4; ++j) acc[i][j] = (f32x4){0.f, 0.f, 0.f, 0.f};

  for (int kt = 0; kt < 32; ++kt) {
    const int k0 = kt * 32;
    const short8 avh0 = *(const short8*)(aghi + k0);
    const short8 avh1 = *(const short8*)(aghi + k0 + 8);
    const short8 avl0 = *(const short8*)(aglo + k0);
    const short8 avl1 = *(const short8*)(aglo + k0 + 8);
    float4 bv0 = *(const float4*)(bg + k0);
    float4 bv1 = *(const float4*)(bg + k0 + 4);
    float4 bv2 = *(const float4*)(bg + k0 + 8);
    float4 bv3 = *(const float4*)(bg + k0 + 12);
    __syncthreads();
    {
      const int off = srow * LDA + scol;
      *(short8*)&Ahi[off] = avh0; *(short8*)&Ahi[off + 8] = avh1;
      *(short8*)&Alo[off] = avl0; *(short8*)&Alo[off + 8] = avl1;
      const float b16[16] = {bv0.x, bv0.y, bv0.z, bv0.w, bv1.x, bv1.y, bv1.z, bv1.w,
                             bv2.x, bv2.y, bv2.z, bv2.w, bv3.x, bv3.y, bv3.z, bv3.w};
      union { unsigned short u[8]; short8 v; } bh0, bl0, bh1, bl1;
#pragma unroll
      for (int e = 0; e < 8; ++e) {
        unsigned short g = f2bf_hi(b16[e]);
        bh0.u[e] = g; bl0.u[e] = f2bf_hi(b16[e] - bf2f(g));
        g = f2bf_hi(b16[e + 8]);
        bh1.u[e] = g; bl1.u[e] = f2bf_hi(b16[e + 8] - bf2f(g));
      }
      *(short8*)&Bhi[off] = bh0.v; *(short8*)&Bhi[off + 8] = bh1.v;
      *(short8*)&Blo[off] = bl0.v; *(short8*)&Blo[off + 8] = bl1.v;
    }
    __syncthreads();
    short8 afh[4], afl[4];
#pragma unroll
    for (int mi = 0; mi < 4; ++mi) {
      const int off = (mw + mi * 16 + l15) * LDA + l4 * 8;
      afh[mi] = *(const short8*)&Ahi[off];
      afl[mi] = *(const short8*)&Alo[off];
    }
#pragma unroll
    for (int ni = 0; ni < 4; ++ni) {
      const int off = (nw + ni * 16 + l15) * LDA + l4 * 8;
      const short8 bfh = *(const short8*)&Bhi[off];
      const short8 bfl = *(const short8*)&Blo[off];
#pragma unroll
      for (int mi = 0; mi < 4; ++mi) {
        acc[mi][ni] = __builtin_amdgcn_mfma_f32_16x16x32_bf16(afh[mi], bfh, acc[mi][ni], 0, 0, 0);
        acc[mi][ni] = __builtin_amdgcn_mfma_f32_16x16x32_bf16(afh[mi], bfl, acc[mi][ni], 0, 0, 0);
        acc[mi][ni] = __builtin_amdgcn_mfma_f32_16x16x32_bf16(afl[mi], bfh, acc[mi][ni], 0, 0, 0);
      }
    }
  }
  float rs[4][4];
#pragma unroll
  for (int mi = 0; mi < 4; ++mi)
#pragma unroll
    for (int reg = 0; reg < 4; ++reg) rs[mi][reg] = 0.f;
#pragma unroll
  for (int ni = 0; ni < 4; ++ni) {
    const int col_l = nw + ni * 16 + l15;
    const float w2v = W2[n0 + col_l];
#pragma unroll
    for (int mi = 0; mi < 4; ++mi) {
      const int rl = mw + mi * 16 + l4 * 4;
#pragma unroll
      for (int reg = 0; reg < 4; ++reg) {
        const int b64 = (rl + reg) & 63;
        const float u = tanhf(acc[mi][ni][reg] + SPs[b64 * 128 + col_l]);
        rs[mi][reg] += u * w2v;
      }
    }
  }
#pragma unroll
  for (int mi = 0; mi < 4; ++mi)
#pragma unroll
    for (int reg = 0; reg < 4; ++reg) {
      float v = rs[mi][reg];
#pragma unroll
      for (int msk = 1; msk < 16; msk <<= 1) v += __shfl_xor(v, msk);
      if (l15 == 0)
        atomicAdd(EP + m0 + mw + mi * 16 + l4 * 4 + reg, v);
    }
}

// ---------------------------------------------------------------------------
// k4: e = tanh(EP + b2); softmax over t (per b)
// ---------------------------------------------------------------------------
__global__ __launch_bounds__(256) void k4_softmax(const float* __restrict__ EP,
    const float* __restrict__ b2, float* __restrict__ AA) {
  const int b = blockIdx.x;
  const int tid = threadIdx.x;
  __shared__ float rbuf[256];
  const float b2v = b2[0];
  const float v0 = tanhf(EP[(size_t)tid * Bn + b] + b2v);
  const float v1 = tanhf(EP[(size_t)(tid + 256) * Bn + b] + b2v);
  rbuf[tid] = fmaxf(v0, v1);
  __syncthreads();
  for (int off = 128; off > 0; off >>= 1) {
    if (tid < off) rbuf[tid] = fmaxf(rbuf[tid], rbuf[tid + off]);
    __syncthreads();
  }
  const float M = rbuf[0];
  __syncthreads();
  const float e0 = expf(v0 - M);
  const float e1 = expf(v1 - M);
  rbuf[tid] = e0 + e1;
  __syncthreads();
  for (int off = 128; off > 0; off >>= 1) {
    if (tid < off) rbuf[tid] = rbuf[tid] + rbuf[tid + off];
    __syncthreads();
  }
  const float S = rbuf[0];
  AA[(size_t)tid * Bn + b] = e0 / S;
  AA[(size_t)(tid + 256) * Bn + b] = e1 / S;
}

// ---------------------------------------------------------------------------
// k5: out[b][n] = sum_t AA[t][b] * (bf2f(Hhi)+bf2f(Hlo))
// ---------------------------------------------------------------------------
__global__ __launch_bounds__(256) void k5_out(const float* __restrict__ AA,
    const unsigned short* __restrict__ Hhi, const unsigned short* __restrict__ Hlo,
    float* __restrict__ out) {
  const int b = blockIdx.x;
  const int n4 = threadIdx.x * 4;
  float o0 = 0.f, o1 = 0.f, o2 = 0.f, o3 = 0.f;
#pragma unroll 4
  for (int t = 0; t < Tn; ++t) {
    const float a = AA[(size_t)t * Bn + b];
    const size_t base = ((size_t)t * Bn + b) * Nn + n4;
    const ushort4 hi = *(const ushort4*)(Hhi + base);
    const ushort4 lo = *(const ushort4*)(Hlo + base);
    o0 += a * (bf2f(hi.x) + bf2f(lo.x));
    o1 += a * (bf2f(hi.y) + bf2f(lo.y));
    o2 += a * (bf2f(hi.z) + bf2f(lo.z));
    o3 += a * (bf2f(hi.w) + bf2f(lo.w));
  }
  float* op = out + (size_t)b * Nn + n4;
  op[0] = o0; op[1] = o1; op[2] = o2; op[3] = o3;
}

// ---------------------------------------------------------------------------
extern "C" void kernel_launch(void* const* d_in, const int* in_sizes, int n_in,
                              void* d_out, int out_size, void* d_ws, size_t ws_size,
                              hipStream_t stream) {
  const float* s     = (const float*)d_in[0];
  const float* x     = (const float*)d_in[1];
  const float* Wih_f = (const float*)d_in[2];
  const float* Whh_f = (const float*)d_in[3];
  const float* bih_f = (const float*)d_in[4];
  const float* bhh_f = (const float*)d_in[5];
  const float* Wih_b = (const float*)d_in[6];
  const float* Whh_b = (const float*)d_in[7];
  const float* bih_b = (const float*)d_in[8];
  const float* bhh_b = (const float*)d_in[9];
  const float* W1    = (const float*)d_in[10];
  const float* b1    = (const float*)d_in[11];
  const float* W2    = (const float*)d_in[12];
  const float* b2    = (const float*)d_in[13];
  float* out = (float*)d_out;

  float* XW = (float*)d_ws;                                  // 134.2 MB f32
  unsigned short* Hhi = (unsigned short*)(XW + 33554432ULL); // 67.1 MB u16
  unsigned short* Hlo = Hhi + 33554432ULL;                   // 67.1 MB u16
  float* SP = (float*)(Hlo + 33554432ULL);                   // 65536 f32
  float* EP = SP + 65536ULL;                                 // 32768 f32
  float* AA = EP + 32768ULL;                                 // 32768 f32
  int* FL   = (int*)(AA + 32768ULL);                         // 2*512*32 ints
  const size_t need = 33554432ULL * 4 + 33554432ULL * 2 * 2 +
                      (65536ULL + 32768 + 32768) * 4 + 32768ULL * 4;
  if (ws_size < need) return;  // workspace too small: fail visibly

  hipMemsetAsync(EP, 0, 32768 * sizeof(float), stream);
  hipMemsetAsync(FL, 0, 32768 * sizeof(int), stream);

  k0_sproj<<<dim3(64), 256, 0, stream>>>(s, W1, b1, SP);
  k1_mfma<<<dim3(8, 256), 256, 0, stream>>>(x, Wih_f, Wih_b, bih_f, bih_b, XW);
  k2_scan_mfma<<<dim3(64), 256, 0, stream>>>(XW, Whh_f, Whh_b, bhh_f, bhh_b, Hhi, Hlo, FL);
  k3_mfma<<<dim3(8, 256), 256, 0, stream>>>(Hhi, Hlo, W1, SP, W2, EP);
  k4_softmax<<<dim3(64), 256, 0, stream>>>(EP, b2, AA);
  k5_out<<<dim3(64), 256, 0, stream>>>(AA, Hhi, Hlo, out);
}

// Round 6
// 2975.993 us; speedup vs baseline: 1.8571x; 1.8571x over previous
//
#include <hip/hip_runtime.h>

#define Tn 512
#define Bn 64
#define Nn 1024
#define Hn 512

typedef __attribute__((ext_vector_type(8))) short short8;
typedef __attribute__((ext_vector_type(4))) float f32x4;
typedef __attribute__((ext_vector_type(4))) int int4v;

__device__ __forceinline__ unsigned short f2bf_hi(float x) {
  unsigned u = __builtin_bit_cast(unsigned, x);
  unsigned r = u + 0x7FFFu + ((u >> 16) & 1u);  // RNE
  return (unsigned short)(r >> 16);
}
__device__ __forceinline__ float bf2f(unsigned short b) {
  unsigned u = ((unsigned)b) << 16;
  return __builtin_bit_cast(float, u);
}

// Frag-major H layout (shorts): idx = (t*2+dir)*32768 + kt*2048 + m*512 + g2*128 + bi*8 + e
//   where within-dir col k = kt*32 + g2*8 + e, batch b = m*16 + bi.
// Consumer wave (m-tile m) A-frag load for k-tile kt is lane-linear: base + lane*8.

// ---------------------------------------------------------------------------
// k0: SP[b][j] = sum_i s[b][i] * W1[j][i]  + b1[j]
// ---------------------------------------------------------------------------
__global__ __launch_bounds__(256) void k0_sproj(const float* __restrict__ s,
    const float* __restrict__ W1, const float* __restrict__ b1,
    float* __restrict__ SP) {
  const int b = blockIdx.x;
  const int tid = threadIdx.x;
  __shared__ float sl[Nn];
  for (int i = tid; i < Nn; i += 256) sl[i] = s[(size_t)b * Nn + i];
  __syncthreads();
#pragma unroll
  for (int qq = 0; qq < 4; ++qq) {
    const int j = qq * 256 + tid;
    const float* w = W1 + (size_t)j * (2 * Nn);
    float acc = 0.f;
    for (int i = 0; i < Nn; i += 4) {
      const float4 wv = *(const float4*)(w + i);
      acc += sl[i] * wv.x + sl[i + 1] * wv.y + sl[i + 2] * wv.z + sl[i + 3] * wv.w;
    }
    SP[(size_t)b * Nn + j] = acc + b1[j];
  }
}

// ---------------------------------------------------------------------------
// k1_mfma: XW = X @ Wcat^T + bias (row-major f32 out)  (UNCHANGED from R4)
// ---------------------------------------------------------------------------
#define LDA 40
__global__ __launch_bounds__(256) void k1_mfma(const float* __restrict__ X,
    const float* __restrict__ Wf, const float* __restrict__ Wb,
    const float* __restrict__ bif, const float* __restrict__ bib,
    float* __restrict__ XW) {
  __shared__ __align__(16) unsigned short Ahi[128 * LDA];
  __shared__ __align__(16) unsigned short Alo[128 * LDA];
  __shared__ __align__(16) unsigned short Bhi[128 * LDA];
  __shared__ __align__(16) unsigned short Blo[128 * LDA];
  const int tid = threadIdx.x;
  const int n0 = blockIdx.x * 128;
  const int m0 = blockIdx.y * 128;
  const int lane = tid & 63;
  const int w = tid >> 6;
  const int mw = (w >> 1) * 64, nw = (w & 1) * 64;
  const int l15 = lane & 15, l4 = lane >> 4;

  const float* bsrc;
  const float* bias_base;
  if (n0 < 512) { bsrc = Wf + (size_t)n0 * Nn; bias_base = bif + n0; }
  else          { bsrc = Wb + (size_t)(n0 - 512) * Nn; bias_base = bib + (n0 - 512); }

  const int srow = tid >> 1, scol = (tid & 1) * 16;
  const float* ag = X + (size_t)(m0 + srow) * Nn + scol;
  const float* bg = bsrc + (size_t)srow * Nn + scol;

  f32x4 acc[4][4];
#pragma unroll
  for (int i = 0; i < 4; ++i)
#pragma unroll
    for (int j = 0; j < 4; ++j) acc[i][j] = (f32x4){0.f, 0.f, 0.f, 0.f};

  for (int kt = 0; kt < 32; ++kt) {
    const int k0 = kt * 32;
    float4 av[4], bv[4];
#pragma unroll
    for (int c = 0; c < 4; ++c) {
      av[c] = *(const float4*)(ag + k0 + c * 4);
      bv[c] = *(const float4*)(bg + k0 + c * 4);
    }
    __syncthreads();
#pragma unroll
    for (int c = 0; c < 4; ++c) {
      const float a4[4] = {av[c].x, av[c].y, av[c].z, av[c].w};
      const float b4[4] = {bv[c].x, bv[c].y, bv[c].z, bv[c].w};
      ushort4 ah, al, bh, bl;
      unsigned short* ahp = (unsigned short*)&ah;
      unsigned short* alp = (unsigned short*)&al;
      unsigned short* bhp = (unsigned short*)&bh;
      unsigned short* blp = (unsigned short*)&bl;
#pragma unroll
      for (int e = 0; e < 4; ++e) {
        const unsigned short h = f2bf_hi(a4[e]);
        ahp[e] = h; alp[e] = f2bf_hi(a4[e] - bf2f(h));
        const unsigned short g = f2bf_hi(b4[e]);
        bhp[e] = g; blp[e] = f2bf_hi(b4[e] - bf2f(g));
      }
      const int off = srow * LDA + scol + c * 4;
      *(ushort4*)&Ahi[off] = ah; *(ushort4*)&Alo[off] = al;
      *(ushort4*)&Bhi[off] = bh; *(ushort4*)&Blo[off] = bl;
    }
    __syncthreads();
    short8 afh[4], afl[4];
#pragma unroll
    for (int mi = 0; mi < 4; ++mi) {
      const int off = (mw + mi * 16 + l15) * LDA + l4 * 8;
      afh[mi] = *(const short8*)&Ahi[off];
      afl[mi] = *(const short8*)&Alo[off];
    }
#pragma unroll
    for (int ni = 0; ni < 4; ++ni) {
      const int off = (nw + ni * 16 + l15) * LDA + l4 * 8;
      const short8 bfh = *(const short8*)&Bhi[off];
      const short8 bfl = *(const short8*)&Blo[off];
#pragma unroll
      for (int mi = 0; mi < 4; ++mi) {
        acc[mi][ni] = __builtin_amdgcn_mfma_f32_16x16x32_bf16(afh[mi], bfh, acc[mi][ni], 0, 0, 0);
        acc[mi][ni] = __builtin_amdgcn_mfma_f32_16x16x32_bf16(afh[mi], bfl, acc[mi][ni], 0, 0, 0);
        acc[mi][ni] = __builtin_amdgcn_mfma_f32_16x16x32_bf16(afl[mi], bfh, acc[mi][ni], 0, 0, 0);
      }
    }
  }
#pragma unroll
  for (int ni = 0; ni < 4; ++ni) {
    const int col = n0 + nw + ni * 16 + l15;
    const float bias = bias_base[nw + ni * 16 + l15];
#pragma unroll
    for (int mi = 0; mi < 4; ++mi) {
      const int row = m0 + mw + mi * 16 + l4 * 4;
#pragma unroll
      for (int reg = 0; reg < 4; ++reg)
        XW[(size_t)(row + reg) * Nn + col] = acc[mi][ni][reg] + bias;
    }
  }
}

// ---------------------------------------------------------------------------
// k2: bidirectional scan, 32 WGs = 2 dir x 16 kt-regions, 512 thr (8 waves).
//   Wave w: m-tile = w&3 (16 batches), col-group = w>>2 (16 of WG's 32 cols).
//   B-frags (Whh) in VGPRs all 512 steps. h kept ONLY in frag-major layout:
//   producer packs via LDS -> 512 contiguous 16B sc0sc1 stores;
//   consumer: lane-linear 1KB wave loads, 4-kt chunks, counted vmcnt(8)
//   double-buffer so LLC latency of chunk j+1 hides under MFMA of chunk j.
// ---------------------------------------------------------------------------
#define K2F 16  // flags (producer WGs) per dir
#define WAITV8 do { asm volatile("s_waitcnt vmcnt(8)" ::: "memory"); __builtin_amdgcn_sched_barrier(0); } while (0)
#define WAITV0 do { asm volatile("s_waitcnt vmcnt(0)" ::: "memory"); __builtin_amdgcn_sched_barrier(0); } while (0)
#define K2_LD(dh, dl, kt) do { \
    const unsigned short* _ph = pbh + (size_t)(kt) * 2048; \
    const unsigned short* _pl = pbl + (size_t)(kt) * 2048; \
    asm volatile("global_load_dwordx4 %0, %1, off sc0 sc1" : "=v"(dh) : "v"(_ph)); \
    asm volatile("global_load_dwordx4 %0, %1, off sc0 sc1" : "=v"(dl) : "v"(_pl)); \
  } while (0)
#define K2_MM(xh, xl, kt) do { \
    const short8 _a = __builtin_bit_cast(short8, xh); \
    const short8 _c = __builtin_bit_cast(short8, xl); \
    a0 = __builtin_amdgcn_mfma_f32_16x16x32_bf16(_a, Bh[kt], a0, 0, 0, 0); \
    a1 = __builtin_amdgcn_mfma_f32_16x16x32_bf16(_a, Bl[kt], a1, 0, 0, 0); \
    a2 = __builtin_amdgcn_mfma_f32_16x16x32_bf16(_c, Bh[kt], a2, 0, 0, 0); \
  } while (0)

__global__ __launch_bounds__(512, 1) void k2_scan_mfma(
    const float* __restrict__ XW,
    const float* __restrict__ Whh_f, const float* __restrict__ Whh_b,
    const float* __restrict__ bhh_f, const float* __restrict__ bhh_b,
    unsigned short* __restrict__ HFhi, unsigned short* __restrict__ HFlo,
    int* __restrict__ FL) {
  const int wg = blockIdx.x;
  const int dir = wg >> 4;
  const int rg = wg & 15;  // kt-region this WG produces (= its out-col block /32)
  const int tid = threadIdx.x;
  const int lane = tid & 63;
  const int w = tid >> 6;
  const int m = w & 3;     // batch-tile
  const int cg = w >> 2;   // col-group within WG (0/1)
  const int l15 = lane & 15, l4 = lane >> 4;
  __shared__ __align__(16) unsigned short PKhi[2048];
  __shared__ __align__(16) unsigned short PKlo[2048];

  const float* Whh = dir ? Whh_b : Whh_f;
  const float* bhh = dir ? bhh_b : bhh_f;
  const int ocol = rg * 32 + cg * 16 + l15;  // within-dir output col (0..511)

  // --- Whh B-frags in VGPRs (once) ---
  short8 Bh[16], Bl[16];
  {
    const float* wr = Whh + (size_t)ocol * Hn;
#pragma unroll
    for (int kt = 0; kt < 16; ++kt) {
      const float4 w0 = *(const float4*)(wr + kt * 32 + l4 * 8);
      const float4 w1 = *(const float4*)(wr + kt * 32 + l4 * 8 + 4);
      const float wf[8] = {w0.x, w0.y, w0.z, w0.w, w1.x, w1.y, w1.z, w1.w};
      union { unsigned short u[8]; short8 v; } hh, ll;
#pragma unroll
      for (int e = 0; e < 8; ++e) {
        const unsigned short h = f2bf_hi(wf[e]);
        hh.u[e] = h; ll.u[e] = f2bf_hi(wf[e] - bf2f(h));
      }
      Bh[kt] = hh.v; Bl[kt] = ll.v;
    }
  }
  const float bhh_c = bhh[ocol];
  // packing indices (epilogue): value (batch bi_=l4*4+reg, col-in-kt cg*16+l15)
  const int g2p = cg * 2 + (l15 >> 3);
  const int ep = l15 & 7;

  for (int t = 0; t < Tn; ++t) {
    const int trow = dir ? (Tn - 1 - t) : t;
    // XW prefetch via asm (issued before poll; poll's internal waits drain it)
    float xw0, xw1, xw2, xw3;
    {
      const float* xp = XW + ((size_t)trow * Bn + m * 16 + l4 * 4) * Nn + dir * 512 + ocol;
      const float* x0 = xp;             const float* x1 = xp + Nn;
      const float* x2 = xp + 2 * Nn;    const float* x3 = xp + 3 * Nn;
      asm volatile("global_load_dword %0, %1, off" : "=v"(xw0) : "v"(x0));
      asm volatile("global_load_dword %0, %1, off" : "=v"(xw1) : "v"(x1));
      asm volatile("global_load_dword %0, %1, off" : "=v"(xw2) : "v"(x2));
      asm volatile("global_load_dword %0, %1, off" : "=v"(xw3) : "v"(x3));
    }

    f32x4 a0 = {0.f, 0.f, 0.f, 0.f}, a1 = a0, a2 = a0;
    if (t > 0) {
      {  // poll the 16 producer flags of (dir, t-1); all waves poll
        int* fp = FL + (size_t)(((dir << 9) | (t - 1))) * K2F;
        while (true) {
          const int v = __hip_atomic_load(fp + (lane & 15), __ATOMIC_RELAXED,
                                          __HIP_MEMORY_SCOPE_AGENT);
          if (__all(v != 0)) break;
          __builtin_amdgcn_s_sleep(1);
        }
      }
      asm volatile("" ::: "memory");
      const int hprow = dir ? (Tn - t) : (t - 1);
      const unsigned short* pbh =
          HFhi + (size_t)(hprow * 2 + dir) * 32768 + m * 512 + lane * 8;
      const unsigned short* pbl =
          HFlo + (size_t)(hprow * 2 + dir) * 32768 + m * 512 + lane * 8;
      int4v Ph[4], Pl[4], Qh[4], Ql[4];
      // chunk pipeline: issue P(kt0-3), Q(kt4-7); wait8 -> mma P; refill P(8-11);
      // wait8 -> mma Q; refill Q(12-15); wait8 -> mma P; wait0 -> mma Q.
      K2_LD(Ph[0], Pl[0], 0);  K2_LD(Ph[1], Pl[1], 1);
      K2_LD(Ph[2], Pl[2], 2);  K2_LD(Ph[3], Pl[3], 3);
      K2_LD(Qh[0], Ql[0], 4);  K2_LD(Qh[1], Ql[1], 5);
      K2_LD(Qh[2], Ql[2], 6);  K2_LD(Qh[3], Ql[3], 7);
      WAITV8;
      K2_MM(Ph[0], Pl[0], 0);  K2_MM(Ph[1], Pl[1], 1);
      K2_MM(Ph[2], Pl[2], 2);  K2_MM(Ph[3], Pl[3], 3);
      K2_LD(Ph[0], Pl[0], 8);  K2_LD(Ph[1], Pl[1], 9);
      K2_LD(Ph[2], Pl[2], 10); K2_LD(Ph[3], Pl[3], 11);
      WAITV8;
      K2_MM(Qh[0], Ql[0], 4);  K2_MM(Qh[1], Ql[1], 5);
      K2_MM(Qh[2], Ql[2], 6);  K2_MM(Qh[3], Ql[3], 7);
      K2_LD(Qh[0], Ql[0], 12); K2_LD(Qh[1], Ql[1], 13);
      K2_LD(Qh[2], Ql[2], 14); K2_LD(Qh[3], Ql[3], 15);
      WAITV8;
      K2_MM(Ph[0], Pl[0], 8);  K2_MM(Ph[1], Pl[1], 9);
      K2_MM(Ph[2], Pl[2], 10); K2_MM(Ph[3], Pl[3], 11);
      WAITV0;
      K2_MM(Qh[0], Ql[0], 12); K2_MM(Qh[1], Ql[1], 13);
      K2_MM(Qh[2], Ql[2], 14); K2_MM(Qh[3], Ql[3], 15);
    }
    WAITV0;  // ensure xw regs landed (no-op when t>0)

    // epilogue: h = tanh(acc + xw + bhh); pack hi/lo into LDS in frag order
#pragma unroll
    for (int reg = 0; reg < 4; ++reg) {
      const float xwv = (reg == 0) ? xw0 : (reg == 1) ? xw1 : (reg == 2) ? xw2 : xw3;
      const float pre = a0[reg] + a1[reg] + a2[reg] + xwv + bhh_c;
      const float h = tanhf(pre);
      const unsigned short hi = f2bf_hi(h);
      const unsigned short lo = f2bf_hi(h - bf2f(hi));
      const int idx = m * 512 + g2p * 128 + (l4 * 4 + reg) * 8 + ep;
      PKhi[idx] = hi;
      PKlo[idx] = lo;
    }
    __syncthreads();
    {  // 512 threads store 16B each: hi region (tid<256) / lo region
      const int half = tid >> 8;
      const int i = tid & 255;
      unsigned short* dst = (half ? HFlo : HFhi) +
          (size_t)(trow * 2 + dir) * 32768 + (size_t)rg * 2048 + (size_t)i * 8;
      const unsigned short* src = (half ? PKlo : PKhi) + i * 8;
      const int4v v = *(const int4v*)src;
      asm volatile("global_store_dwordx4 %0, %1, off sc0 sc1" :: "v"(dst), "v"(v) : "memory");
    }
    asm volatile("s_waitcnt vmcnt(0)" ::: "memory");
    __syncthreads();  // all waves drained; LDS safe to reuse next step
    if (tid == 0)
      __hip_atomic_store(FL + (size_t)(((dir << 9) | t)) * K2F + rg, 1,
                         __ATOMIC_RELAXED, __HIP_MEMORY_SCOPE_AGENT);
  }
}

// ---------------------------------------------------------------------------
// k3_mfma: EP[m] += sum_j W2[j]*tanh(sum_k H[m][k]*W1[j][N+k] + SP[b][j])
//   A sourced from frag-major HFhi/HFlo (granule-indexed 16B loads).
// ---------------------------------------------------------------------------
__global__ __launch_bounds__(256) void k3_mfma(
    const unsigned short* __restrict__ Hhi, const unsigned short* __restrict__ Hlo,
    const float* __restrict__ W1, const float* __restrict__ SP,
    const float* __restrict__ W2, float* __restrict__ EP) {
  __shared__ __align__(16) unsigned short Ahi[128 * LDA];
  __shared__ __align__(16) unsigned short Alo[128 * LDA];
  __shared__ __align__(16) unsigned short Bhi[128 * LDA];
  __shared__ __align__(16) unsigned short Blo[128 * LDA];
  __shared__ __align__(16) float SPs[64 * 128];
  const int tid = threadIdx.x;
  const int n0 = blockIdx.x * 128;
  const int m0 = blockIdx.y * 128;
  const int lane = tid & 63;
  const int w = tid >> 6;
  const int mw = (w >> 1) * 64, nw = (w & 1) * 64;
  const int l15 = lane & 15, l4 = lane >> 4;

  {
    const int r64 = tid >> 2, c0 = (tid & 3) * 32;
    const float* sps = SP + (size_t)r64 * Nn + n0 + c0;
    float* spd = &SPs[r64 * 128 + c0];
#pragma unroll
    for (int c = 0; c < 8; ++c) *(float4*)(spd + c * 4) = *(const float4*)(sps + c * 4);
  }

  const int srow = tid >> 1, scol = (tid & 1) * 16;
  const int tb = m0 + srow;
  const int t3 = tb >> 6, b3 = tb & 63;
  // abase: frag-major offset without the (dir,kt,g2) part
  const size_t abase = (size_t)t3 * 65536 + (size_t)(b3 >> 4) * 512 + (size_t)(b3 & 15) * 8
                     + (size_t)(scol >> 3) * 128;
  const float* bg = W1 + (size_t)(n0 + srow) * (2 * Nn) + Nn + scol;

  f32x4 acc[4][4];
#pragma unroll
  for (int i = 0; i < 4; ++i)
#pragma unroll
    for (int j = 0; j < 4; ++j) acc[i][j] = (f32x4){0.f, 0.f, 0.f, 0.f};

  for (int kt = 0; kt < 32; ++kt) {
    const int k0 = kt * 32;
    const size_t gidx = abase + (size_t)(kt >> 4) * 32768 + (size_t)(kt & 15) * 2048;
    const short8 avh0 = *(const short8*)(Hhi + gidx);
    const short8 avh1 = *(const short8*)(Hhi + gidx + 128);
    const short8 avl0 = *(const short8*)(Hlo + gidx);
    const short8 avl1 = *(const short8*)(Hlo + gidx + 128);
    float4 bv0 = *(const float4*)(bg + k0);
    float4 bv1 = *(const float4*)(bg + k0 + 4);
    float4 bv2 = *(const float4*)(bg + k0 + 8);
    float4 bv3 = *(const float4*)(bg + k0 + 12);
    __syncthreads();
    {
      const int off = srow * LDA + scol;
      *(short8*)&Ahi[off] = avh0; *(short8*)&Ahi[off + 8] = avh1;
      *(short8*)&Alo[off] = avl0; *(short8*)&Alo[off + 8] = avl1;
      const float b16[16] = {bv0.x, bv0.y, bv0.z, bv0.w, bv1.x, bv1.y, bv1.z, bv1.w,
                             bv2.x, bv2.y, bv2.z, bv2.w, bv3.x, bv3.y, bv3.z, bv3.w};
      union { unsigned short u[8]; short8 v; } bh0, bl0, bh1, bl1;
#pragma unroll
      for (int e = 0; e < 8; ++e) {
        unsigned short g = f2bf_hi(b16[e]);
        bh0.u[e] = g; bl0.u[e] = f2bf_hi(b16[e] - bf2f(g));
        g = f2bf_hi(b16[e + 8]);
        bh1.u[e] = g; bl1.u[e] = f2bf_hi(b16[e + 8] - bf2f(g));
      }
      *(short8*)&Bhi[off] = bh0.v; *(short8*)&Bhi[off + 8] = bh1.v;
      *(short8*)&Blo[off] = bl0.v; *(short8*)&Blo[off + 8] = bl1.v;
    }
    __syncthreads();
    short8 afh[4], afl[4];
#pragma unroll
    for (int mi = 0; mi < 4; ++mi) {
      const int off = (mw + mi * 16 + l15) * LDA + l4 * 8;
      afh[mi] = *(const short8*)&Ahi[off];
      afl[mi] = *(const short8*)&Alo[off];
    }
#pragma unroll
    for (int ni = 0; ni < 4; ++ni) {
      const int off = (nw + ni * 16 + l15) * LDA + l4 * 8;
      const short8 bfh = *(const short8*)&Bhi[off];
      const short8 bfl = *(const short8*)&Blo[off];
#pragma unroll
      for (int mi = 0; mi < 4; ++mi) {
        acc[mi][ni] = __builtin_amdgcn_mfma_f32_16x16x32_bf16(afh[mi], bfh, acc[mi][ni], 0, 0, 0);
        acc[mi][ni] = __builtin_amdgcn_mfma_f32_16x16x32_bf16(afh[mi], bfl, acc[mi][ni], 0, 0, 0);
        acc[mi][ni] = __builtin_amdgcn_mfma_f32_16x16x32_bf16(afl[mi], bfh, acc[mi][ni], 0, 0, 0);
      }
    }
  }
  float rs[4][4];
#pragma unroll
  for (int mi = 0; mi < 4; ++mi)
#pragma unroll
    for (int reg = 0; reg < 4; ++reg) rs[mi][reg] = 0.f;
#pragma unroll
  for (int ni = 0; ni < 4; ++ni) {
    const int col_l = nw + ni * 16 + l15;
    const float w2v = W2[n0 + col_l];
#pragma unroll
    for (int mi = 0; mi < 4; ++mi) {
      const int rl = mw + mi * 16 + l4 * 4;
#pragma unroll
      for (int reg = 0; reg < 4; ++reg) {
        const int b64 = (rl + reg) & 63;
        const float u = tanhf(acc[mi][ni][reg] + SPs[b64 * 128 + col_l]);
        rs[mi][reg] += u * w2v;
      }
    }
  }
#pragma unroll
  for (int mi = 0; mi < 4; ++mi)
#pragma unroll
    for (int reg = 0; reg < 4; ++reg) {
      float v = rs[mi][reg];
#pragma unroll
      for (int msk = 1; msk < 16; msk <<= 1) v += __shfl_xor(v, msk);
      if (l15 == 0)
        atomicAdd(EP + m0 + mw + mi * 16 + l4 * 4 + reg, v);
    }
}

// ---------------------------------------------------------------------------
// k4: e = tanh(EP + b2); softmax over t (per b)
// ---------------------------------------------------------------------------
__global__ __launch_bounds__(256) void k4_softmax(const float* __restrict__ EP,
    const float* __restrict__ b2, float* __restrict__ AA) {
  const int b = blockIdx.x;
  const int tid = threadIdx.x;
  __shared__ float rbuf[256];
  const float b2v = b2[0];
  const float v0 = tanhf(EP[(size_t)tid * Bn + b] + b2v);
  const float v1 = tanhf(EP[(size_t)(tid + 256) * Bn + b] + b2v);
  rbuf[tid] = fmaxf(v0, v1);
  __syncthreads();
  for (int off = 128; off > 0; off >>= 1) {
    if (tid < off) rbuf[tid] = fmaxf(rbuf[tid], rbuf[tid + off]);
    __syncthreads();
  }
  const float M = rbuf[0];
  __syncthreads();
  const float e0 = expf(v0 - M);
  const float e1 = expf(v1 - M);
  rbuf[tid] = e0 + e1;
  __syncthreads();
  for (int off = 128; off > 0; off >>= 1) {
    if (tid < off) rbuf[tid] = rbuf[tid] + rbuf[tid + off];
    __syncthreads();
  }
  const float S = rbuf[0];
  AA[(size_t)tid * Bn + b] = e0 / S;
  AA[(size_t)(tid + 256) * Bn + b] = e1 / S;
}

// ---------------------------------------------------------------------------
// k5: out[b][n] = sum_t AA[t][b]*(hi+lo), frag-major reads, bi-coalesced grid
//   grid (4 m-tiles, 16 col-chunks), block 256: tid = ns*16 + bi
// ---------------------------------------------------------------------------
__global__ __launch_bounds__(256) void k5_out(const float* __restrict__ AA,
    const unsigned short* __restrict__ Hhi, const unsigned short* __restrict__ Hlo,
    float* __restrict__ out) {
  const int tid = threadIdx.x;
  const int bi = tid & 15;
  const int ns = tid >> 4;
  const int mb = blockIdx.x;           // batch tile
  const int b = mb * 16 + bi;
  const int n4 = blockIdx.y * 64 + ns * 4;
  const int p = n4;
  const size_t base = (size_t)(p >> 9) * 32768 + (size_t)((p & 511) >> 5) * 2048 +
                      (size_t)mb * 512 + (size_t)((p & 31) >> 3) * 128 +
                      (size_t)bi * 8 + (p & 7);
  float o0 = 0.f, o1 = 0.f, o2 = 0.f, o3 = 0.f;
  for (int t = 0; t < Tn; ++t) {
    const float a = AA[(size_t)t * Bn + b];
    const size_t idx = (size_t)t * 65536 + base;
    const ushort4 hi = *(const ushort4*)(Hhi + idx);
    const ushort4 lo = *(const ushort4*)(Hlo + idx);
    o0 += a * (bf2f(hi.x) + bf2f(lo.x));
    o1 += a * (bf2f(hi.y) + bf2f(lo.y));
    o2 += a * (bf2f(hi.z) + bf2f(lo.z));
    o3 += a * (bf2f(hi.w) + bf2f(lo.w));
  }
  float* op = out + (size_t)b * Nn + n4;
  op[0] = o0; op[1] = o1; op[2] = o2; op[3] = o3;
}

// ---------------------------------------------------------------------------
extern "C" void kernel_launch(void* const* d_in, const int* in_sizes, int n_in,
                              void* d_out, int out_size, void* d_ws, size_t ws_size,
                              hipStream_t stream) {
  const float* s     = (const float*)d_in[0];
  const float* x     = (const float*)d_in[1];
  const float* Wih_f = (const float*)d_in[2];
  const float* Whh_f = (const float*)d_in[3];
  const float* bih_f = (const float*)d_in[4];
  const float* bhh_f = (const float*)d_in[5];
  const float* Wih_b = (const float*)d_in[6];
  const float* Whh_b = (const float*)d_in[7];
  const float* bih_b = (const float*)d_in[8];
  const float* bhh_b = (const float*)d_in[9];
  const float* W1    = (const float*)d_in[10];
  const float* b1    = (const float*)d_in[11];
  const float* W2    = (const float*)d_in[12];
  const float* b2    = (const float*)d_in[13];
  float* out = (float*)d_out;

  float* XW = (float*)d_ws;                                  // 134.2 MB f32
  unsigned short* Hhi = (unsigned short*)(XW + 33554432ULL); // 67.1 MB u16 (frag-major)
  unsigned short* Hlo = Hhi + 33554432ULL;                   // 67.1 MB u16
  float* SP = (float*)(Hlo + 33554432ULL);                   // 65536 f32
  float* EP = SP + 65536ULL;                                 // 32768 f32
  float* AA = EP + 32768ULL;                                 // 32768 f32
  int* FL   = (int*)(AA + 32768ULL);                         // 2*512*16 ints
  const size_t need = 33554432ULL * 4 + 33554432ULL * 2 * 2 +
                      (65536ULL + 32768 + 32768) * 4 + 16384ULL * 4;
  if (ws_size < need) return;  // workspace too small: fail visibly

  hipMemsetAsync(EP, 0, 32768 * sizeof(float), stream);
  hipMemsetAsync(FL, 0, 16384 * sizeof(int), stream);

  k0_sproj<<<dim3(64), 256, 0, stream>>>(s, W1, b1, SP);
  k1_mfma<<<dim3(8, 256), 256, 0, stream>>>(x, Wih_f, Wih_b, bih_f, bih_b, XW);
  k2_scan_mfma<<<dim3(32), 512, 0, stream>>>(XW, Whh_f, Whh_b, bhh_f, bhh_b, Hhi, Hlo, FL);
  k3_mfma<<<dim3(8, 256), 256, 0, stream>>>(Hhi, Hlo, W1, SP, W2, EP);
  k4_softmax<<<dim3(64), 256, 0, stream>>>(EP, b2, AA);
  k5_out<<<dim3(4, 16), 256, 0, stream>>>(AA, Hhi, Hlo, out);
}